// Round 4
// baseline (344.790 us; speedup 1.0000x reference)
//
#include <hip/hip_runtime.h>
#include <stdint.h>

// Problem constants (fixed by setup_inputs): B=2, C=80, A=1024, H=W=2048
#define BATCH 2
#define NCLS 80
#define NP (BATCH * NCLS)   // 160 independent NMS problems
#define NA 1024
#define NWORD 16            // NA/64
#define IMG_W 2048.0f
#define IMG_H 2048.0f

// monotone float -> uint mapping (ascending uint order == ascending float order)
__device__ __forceinline__ unsigned enc_f32(float f) {
  unsigned u = __float_as_uint(f);
  return (u & 0x80000000u) ? ~u : (u | 0x80000000u);
}

// ---------------------------------------------------------------------------
// K1: decode boxes, build stable sort keys, bitonic sort (verified round-2).
//   skeyG[p][r]  u64: enc(-score or +inf)<<32 | orig_idx (ascending = score desc)
//   sboxG[p][r]  float4 box in sorted order
//   nvalidG[p]   count of scores > 0.05
// ---------------------------------------------------------------------------
__global__ __launch_bounds__(256) void decode_sort_kernel(
    const float* __restrict__ cls_pred,   // (B, C, A)
    const float* __restrict__ reg_pred,   // (B, 4, A)
    const float* __restrict__ anchors,    // (A, 4)
    unsigned long long* __restrict__ skeyG,  // (NP, NA)
    float4* __restrict__ sboxG,              // (NP, NA)
    int* __restrict__ nvalidG)               // (NP)
{
#pragma clang fp contract(off)
  const int bc  = blockIdx.x;
  const int b   = bc / NCLS;
  const int tid = threadIdx.x;

  __shared__ __align__(16) float4 obox[NA];            // 16 KB
  __shared__ unsigned long long skey[NA];              // 8 KB
  __shared__ int cntS;

  if (tid == 0) cntS = 0;
  __syncthreads();

  const float* regb = reg_pred + (size_t)b * 4 * NA;
  const float* scb  = cls_pred + (size_t)bc * NA;
  int localcnt = 0;
  for (int a = tid; a < NA; a += 256) {
    float4 an = ((const float4*)anchors)[a];
    float w  = an.z - an.x;
    float h  = an.w - an.y;
    float cx = an.x + 0.5f * w;
    float cy = an.y + 0.5f * h;
    float dx = regb[0 * NA + a] * 0.1f;
    float dy = regb[1 * NA + a] * 0.1f;
    float dw = regb[2 * NA + a] * 0.2f;
    float dh = regb[3 * NA + a] * 0.2f;
    float pcx = cx + dx * w;
    float pcy = cy + dy * h;
    float pw  = expf(dw) * w;
    float ph  = expf(dh) * h;
    float x1 = fmaxf(pcx - 0.5f * pw, 0.0f);
    float y1 = pcy - 0.5f * ph;
    x1 = fmaxf(x1, 0.0f);
    y1 = fmaxf(y1, 0.0f);
    float x2 = fminf(pcx + 0.5f * pw, IMG_W);
    float y2 = fminf(pcy + 0.5f * ph, IMG_H);
    obox[a] = make_float4(x1, y1, x2, y2);

    float s    = scb[a];
    bool valid = (s > 0.05f);
    localcnt  += valid ? 1 : 0;
    float key  = valid ? -s : __int_as_float(0x7f800000);  // +inf if invalid
    skey[a] = ((unsigned long long)enc_f32(key) << 32) | (unsigned)a;
  }
  atomicAdd(&cntS, localcnt);
  __syncthreads();

  // stable bitonic sort ascending (unique keys: idx in low 32 bits)
  for (int k = 2; k <= NA; k <<= 1) {
    for (int j = k >> 1; j > 0; j >>= 1) {
      for (int m = tid; m < NA; m += 256) {
        int mx = m ^ j;
        if (mx > m) {
          unsigned long long va = skey[m];
          unsigned long long vb = skey[mx];
          bool up = ((m & k) == 0);
          if ((va > vb) == up) { skey[m] = vb; skey[mx] = va; }
        }
      }
      __syncthreads();
    }
  }

  unsigned long long* pk = skeyG + (size_t)bc * NA;
  float4* pb = sboxG + (size_t)bc * NA;
#pragma unroll
  for (int m = 0; m < 4; ++m) {
    int r = tid + m * 256;
    unsigned long long kv = skey[r];
    int orig = (int)(unsigned)kv;
    pk[r] = kv;
    pb[r] = obox[orig];
  }
  if (tid == 0) nvalidG[bc] = cntS;
}

// ---------------------------------------------------------------------------
// K2: suppression bitmask matrix, transposed layout masks[p][w][row].
// Grid (10, NP) x 256 threads. Each wave = one task (w, g): column word w,
// rows [256g, 256g+256). Each lane register-caches 4 row boxes, so one LDS
// broadcast of column box j feeds 4 IOUs (VALU-bound by design).
// Rows >= nv or row-blocks > w produce garbage/no writes; never read by K3.
// Exact-rounding predicate == reference's RN(inter/un) > 0.5 (verified r3):
//   (2*inter - un) > un * 2^-24
// ---------------------------------------------------------------------------
__global__ __launch_bounds__(256) void mask_kernel(
    const float4* __restrict__ sboxG,
    const int* __restrict__ nvalidG,
    unsigned long long* __restrict__ masksG)   // (NP, NWORD, NA)
{
#pragma clang fp contract(off)
  const int p      = blockIdx.y;
  const int q      = blockIdx.x;       // 0..9
  const int tid    = threadIdx.x;
  const int waveId = tid >> 6;
  const int lane   = tid & 63;

  __shared__ __align__(16) float4 sb[NA];   // 16 KB
  __shared__ float sa[NA];                  // 4 KB

  const float4* pb = sboxG + (size_t)p * NA;
  for (int r = tid; r < NA; r += 256) {
    float4 bx = pb[r];
    sb[r] = bx;
    sa[r] = (bx.z - bx.x) * (bx.w - bx.y);
  }
  const int nv = nvalidG[p];
  __syncthreads();

  // task id -> (w, g):  counts per w: w<4:1, w<8:2, w<12:3, w<16:4  (40 total)
  const int t = q * 4 + waveId;
  int w, g;
  if (t < 4)       { w = t;              g = 0; }
  else if (t < 12) { int i = t - 4;  w = 4  + (i >> 1); g = i & 1; }
  else if (t < 24) { int i = t - 12; w = 8  + i / 3;    g = i % 3; }
  else             { int i = t - 24; w = 12 + (i >> 2); g = i & 3; }

  if (w * 64 >= nv) return;   // all columns invalid -> words never read

  float4 bi[4]; float ai[4];
  unsigned long long bits[4] = {0ull, 0ull, 0ull, 0ull};
  const int rbase = g * 256 + lane;
#pragma unroll
  for (int k = 0; k < 4; ++k) {
    int r = rbase + 64 * k;
    bi[k] = sb[r];
    ai[k] = sa[r];
  }

  const int jbase = w * 64;
#pragma unroll 8
  for (int jj = 0; jj < 64; ++jj) {
    float4 bj = sb[jbase + jj];    // wave-broadcast
    float  aj = sa[jbase + jj];
#pragma unroll
    for (int k = 0; k < 4; ++k) {
      float ix1 = fmaxf(bi[k].x, bj.x);
      float iy1 = fmaxf(bi[k].y, bj.y);
      float ix2 = fminf(bi[k].z, bj.z);
      float iy2 = fminf(bi[k].w, bj.w);
      float inter = fmaxf(ix2 - ix1, 0.0f) * fmaxf(iy2 - iy1, 0.0f);
      float un = fmaxf((ai[k] + aj) - inter, 1e-9f);
      bool sup = ((inter + inter) - un) > un * 5.9604644775390625e-8f;
      bits[k] |= sup ? (1ull << jj) : 0ull;
    }
  }

  // coalesced stores: 64 consecutive u64 per row-block
  unsigned long long* pw = masksG + ((size_t)p * NWORD + w) * NA;
#pragma unroll
  for (int k = 0; k < 4; ++k) {
    int rb = g * 4 + k;
    if (rb > w) break;                 // wave-uniform
    unsigned long long bv = bits[k];
    if (rb == w)                       // diagonal word: only j > i counts
      bv &= (lane == 63) ? 0ull : ((~0ull) << (lane + 1));
    pw[rb * 64 + lane] = bv;
  }
}

// ---------------------------------------------------------------------------
// K3: greedy scan + output. One wave per problem, no block barriers in the
// chunk loop: rem[] lane-indexed in registers, diag prefetched a chunk ahead,
// kept is wave-uniform out of the ballot loop.
// ---------------------------------------------------------------------------
__global__ __launch_bounds__(64) void scan_kernel(
    const unsigned long long* __restrict__ skeyG,
    const float4* __restrict__ sboxG,
    const unsigned long long* __restrict__ masksG,   // (NP, NWORD, NA)
    const int* __restrict__ nvalidG,
    float* __restrict__ out)              // (NP, NA, 5)
{
  const int p    = blockIdx.x;
  const int lane = threadIdx.x;

  __shared__ unsigned long long keptS[NWORD];
  __shared__ __align__(16) float outAll[NA * 5];   // 20 KB

  if (lane < NWORD) keptS[lane] = 0ull;

  const int nv = nvalidG[p];
  const int nchunk = (nv + 63) >> 6;
  const unsigned long long* pm = masksG + (size_t)p * NWORD * NA;

  unsigned long long remReg = 0ull;   // lane w (w<16): rem word w
  unsigned long long diag = 0ull;
  if (nchunk > 0 && lane < nv) diag = pm[lane];   // word 0, rows 0..63

  for (int c = 0; c < nchunk; ++c) {
    // prefetch next chunk's diagonal early (hides load latency)
    unsigned long long diagN = 0ull;
    {
      int nrow = (c + 1) * 64 + lane;
      if (c + 1 < nchunk && nrow < nv)
        diagN = pm[(size_t)(c + 1) * NA + nrow];
    }

    int kmax = nv - c * 64; if (kmax > 64) kmax = 64;
    unsigned long long S = __shfl(remReg, c);
    bool alive = (lane < kmax) && !((S >> lane) & 1ull);
    unsigned long long kept = 0ull;
    while (true) {
      unsigned long long mb = __ballot(alive);
      if (!mb) break;
      int r = __builtin_ctzll(mb);
      kept |= (1ull << r);
      unsigned long long supw = __shfl(diag, r);
      alive = alive && (lane != r) && !((supw >> lane) & 1ull);
    }
    if (lane == 0) keptS[c] = kept;

    // OR kept rows' words into rem (lanes: w = lane&15, 4 k-groups of 16)
    int w = lane & 15, grp = lane >> 4;
    unsigned long long acc = 0ull;
    if (w > c) {
      const unsigned long long* pww = pm + (size_t)w * NA + c * 64;
#pragma unroll 4
      for (int kk = 0; kk < 16; ++kk) {
        int k = grp * 16 + kk;
        if ((kept >> k) & 1ull) acc |= pww[k];
      }
    }
    acc |= __shfl_xor(acc, 16);
    acc |= __shfl_xor(acc, 32);
    remReg |= acc;      // lanes >=16 hold consistent copies; lane c<16 read
    diag = diagN;
  }
  __syncthreads();   // make keptS (lane-0 LDS writes) visible to all lanes

  // stage output in original anchor order
  const unsigned long long* pk = skeyG + (size_t)p * NA;
  const float4* pb = sboxG + (size_t)p * NA;
#pragma unroll 4
  for (int it = 0; it < NWORD; ++it) {
    int r = it * 64 + lane;
    unsigned long long kv = pk[r];
    float4 bx = pb[r];
    int orig = (int)(unsigned)kv;
    bool kp = (keptS[it] >> lane) & 1ull;
    float sc = 0.0f;
    float4 ob = make_float4(0.0f, 0.0f, 0.0f, 0.0f);
    if (kp) {
      sc = -__uint_as_float(~(unsigned)(kv >> 32));  // exact original score
      ob = bx;
    }
    float* oa = outAll + (size_t)orig * 5;
    oa[0] = sc; oa[1] = ob.x; oa[2] = ob.y; oa[3] = ob.z; oa[4] = ob.w;
  }
  __syncthreads();   // cross-lane LDS scatter -> ordered reads

  float4* og = (float4*)(out + (size_t)p * NA * 5);
  const float4* ol = (const float4*)outAll;
  for (int t4 = lane; t4 < (NA * 5) / 4; t4 += 64) og[t4] = ol[t4];
}

// ---------------------------------------------------------------------------
// Fallback: round-1 monolithic kernel (used only if ws_size is too small)
// ---------------------------------------------------------------------------
__global__ __launch_bounds__(256) void nms_mono_kernel(
    const float* __restrict__ cls_pred,
    const float* __restrict__ reg_pred,
    const float* __restrict__ anchors,
    float* __restrict__ out)
{
#pragma clang fp contract(off)
  const int bc  = blockIdx.x;
  const int b   = bc / NCLS;
  const int tid = threadIdx.x;
  const int BNT = 256, BPT = 4;

  __shared__ __align__(16) unsigned char smem[49152];
  float4*             obox  = (float4*)(smem);
  float4*             sbox  = (float4*)(smem + 16384);
  unsigned long long* skey  = (unsigned long long*)(smem + 32768);
  float*              sarea = (float*)(smem + 40960);
  int*                keepL = (int*)(smem + 45056);

  const float* regb = reg_pred + (size_t)b * 4 * NA;
  const float* scb  = cls_pred + (size_t)bc * NA;
  for (int a = tid; a < NA; a += BNT) {
    float4 an = ((const float4*)anchors)[a];
    float w  = an.z - an.x;
    float h  = an.w - an.y;
    float cx = an.x + 0.5f * w;
    float cy = an.y + 0.5f * h;
    float dx = regb[0 * NA + a] * 0.1f;
    float dy = regb[1 * NA + a] * 0.1f;
    float dw = regb[2 * NA + a] * 0.2f;
    float dh = regb[3 * NA + a] * 0.2f;
    float pcx = cx + dx * w;
    float pcy = cy + dy * h;
    float pw  = expf(dw) * w;
    float ph  = expf(dh) * h;
    float x1 = fmaxf(fmaxf(pcx - 0.5f * pw, 0.0f), 0.0f);
    float y1 = fmaxf(pcy - 0.5f * ph, 0.0f);
    float x2 = fminf(pcx + 0.5f * pw, IMG_W);
    float y2 = fminf(pcy + 0.5f * ph, IMG_H);
    obox[a] = make_float4(x1, y1, x2, y2);
    float s   = scb[a];
    float key = (s > 0.05f) ? -s : __int_as_float(0x7f800000);
    skey[a] = ((unsigned long long)enc_f32(key) << 32) | (unsigned)a;
  }
  __syncthreads();
  for (int k = 2; k <= NA; k <<= 1) {
    for (int j = k >> 1; j > 0; j >>= 1) {
      for (int m = tid; m < NA; m += BNT) {
        int mx = m ^ j;
        if (mx > m) {
          unsigned long long va = skey[m];
          unsigned long long vb = skey[mx];
          bool up = ((m & k) == 0);
          if ((va > vb) == up) { skey[m] = vb; skey[mx] = va; }
        }
      }
      __syncthreads();
    }
  }
  float4 bj[4]; float aj[4]; int kj[4];
#pragma unroll
  for (int m = 0; m < BPT; ++m) {
    int r = tid + m * BNT;
    unsigned long long kv = skey[r];
    int orig = (int)(unsigned)kv;
    float4 bx = obox[orig];
    sbox[r] = bx;
    float ar = (bx.z - bx.x) * (bx.w - bx.y);
    sarea[r] = ar;
    int kp = ((unsigned)(kv >> 32) != 0xFF800000u) ? 1 : 0;
    keepL[r] = kp;
    bj[m] = bx; aj[m] = ar; kj[m] = kp;
  }
  for (int i = 0; i < NA; ++i) {
    __syncthreads();
    if (keepL[i] == 0) continue;
    float4 bi = sbox[i];
    float  ai = sarea[i];
#pragma unroll
    for (int m = 0; m < BPT; ++m) {
      int j = tid + m * BNT;
      if (j > i && kj[m]) {
        float ix1 = fmaxf(bi.x, bj[m].x);
        float iy1 = fmaxf(bi.y, bj[m].y);
        float ix2 = fminf(bi.z, bj[m].z);
        float iy2 = fminf(bi.w, bj[m].w);
        float inter = fmaxf(ix2 - ix1, 0.0f) * fmaxf(iy2 - iy1, 0.0f);
        float un = fmaxf(ai + aj[m] - inter, 1e-9f);
        if (inter / un > 0.5f) { kj[m] = 0; keepL[j] = 0; }
      }
    }
  }
  __syncthreads();
  float4* outbox = obox;
  float*  outsc  = sarea;
#pragma unroll
  for (int m = 0; m < BPT; ++m) {
    int r = tid + m * BNT;
    unsigned long long kv = skey[r];
    int orig = (int)(unsigned)kv;
    float  sc = 0.0f;
    float4 bx = make_float4(0.0f, 0.0f, 0.0f, 0.0f);
    if (kj[m]) {
      sc = -__uint_as_float(~(unsigned)(kv >> 32));
      bx = sbox[r];
    }
    outsc[orig]  = sc;
    outbox[orig] = bx;
  }
  __syncthreads();
  float* ob = out + (size_t)bc * NA * 5;
  for (int a = tid; a < NA; a += BNT) {
    float4 bx = outbox[a];
    float* o = ob + (size_t)a * 5;
    o[0] = outsc[a]; o[1] = bx.x; o[2] = bx.y; o[3] = bx.z; o[4] = bx.w;
  }
}

// ---------------------------------------------------------------------------
extern "C" void kernel_launch(void* const* d_in, const int* in_sizes, int n_in,
                              void* d_out, int out_size, void* d_ws, size_t ws_size,
                              hipStream_t stream) {
  const float* cls = (const float*)d_in[1];
  const float* reg = (const float*)d_in[2];
  const float* anc = (const float*)d_in[3];
  float* out = (float*)d_out;

  // workspace layout (256B-aligned blocks)
  const size_t off_key  = 0;                                    // NP*NA*8
  const size_t off_box  = off_key + (size_t)NP * NA * 8;        // NP*NA*16
  const size_t off_mask = off_box + (size_t)NP * NA * 16;       // NP*NWORD*NA*8
  const size_t off_nv   = off_mask + (size_t)NP * NWORD * NA * 8;
  const size_t need     = off_nv + (size_t)NP * sizeof(int);

  if (ws_size < need) {
    nms_mono_kernel<<<dim3(NP), dim3(256), 0, stream>>>(cls, reg, anc, out);
    return;
  }

  char* ws = (char*)d_ws;
  unsigned long long* skeyG = (unsigned long long*)(ws + off_key);
  float4*             sboxG = (float4*)(ws + off_box);
  unsigned long long* masks = (unsigned long long*)(ws + off_mask);
  int*                nvG   = (int*)(ws + off_nv);

  decode_sort_kernel<<<dim3(NP), dim3(256), 0, stream>>>(cls, reg, anc, skeyG, sboxG, nvG);
  mask_kernel<<<dim3(10, NP), dim3(256), 0, stream>>>(sboxG, nvG, masks);
  scan_kernel<<<dim3(NP), dim3(64), 0, stream>>>(skeyG, sboxG, masks, nvG, out);
}

// Round 5
// 237.975 us; speedup vs baseline: 1.4488x; 1.4488x over previous
//
#include <hip/hip_runtime.h>
#include <stdint.h>

// Problem constants (fixed by setup_inputs): B=2, C=80, A=1024, H=W=2048
#define BATCH 2
#define NCLS 80
#define NP (BATCH * NCLS)   // 160 independent NMS problems
#define NA 1024
#define NWORD 16            // NA/64
#define IMG_W 2048.0f
#define IMG_H 2048.0f

// monotone float -> uint mapping (ascending uint order == ascending float order)
__device__ __forceinline__ unsigned enc_f32(float f) {
  unsigned u = __float_as_uint(f);
  return (u & 0x80000000u) ? ~u : (u | 0x80000000u);
}

// ---------------------------------------------------------------------------
// K1: decode boxes, build stable sort keys, bitonic sort (verified r2-r4).
// ---------------------------------------------------------------------------
__global__ __launch_bounds__(256) void decode_sort_kernel(
    const float* __restrict__ cls_pred,   // (B, C, A)
    const float* __restrict__ reg_pred,   // (B, 4, A)
    const float* __restrict__ anchors,    // (A, 4)
    unsigned long long* __restrict__ skeyG,  // (NP, NA)
    float4* __restrict__ sboxG,              // (NP, NA)
    int* __restrict__ nvalidG)               // (NP)
{
#pragma clang fp contract(off)
  const int bc  = blockIdx.x;
  const int b   = bc / NCLS;
  const int tid = threadIdx.x;

  __shared__ __align__(16) float4 obox[NA];            // 16 KB
  __shared__ unsigned long long skey[NA];              // 8 KB
  __shared__ int cntS;

  if (tid == 0) cntS = 0;
  __syncthreads();

  const float* regb = reg_pred + (size_t)b * 4 * NA;
  const float* scb  = cls_pred + (size_t)bc * NA;
  int localcnt = 0;
  for (int a = tid; a < NA; a += 256) {
    float4 an = ((const float4*)anchors)[a];
    float w  = an.z - an.x;
    float h  = an.w - an.y;
    float cx = an.x + 0.5f * w;
    float cy = an.y + 0.5f * h;
    float dx = regb[0 * NA + a] * 0.1f;
    float dy = regb[1 * NA + a] * 0.1f;
    float dw = regb[2 * NA + a] * 0.2f;
    float dh = regb[3 * NA + a] * 0.2f;
    float pcx = cx + dx * w;
    float pcy = cy + dy * h;
    float pw  = expf(dw) * w;
    float ph  = expf(dh) * h;
    float x1 = fmaxf(pcx - 0.5f * pw, 0.0f);
    float y1 = pcy - 0.5f * ph;
    x1 = fmaxf(x1, 0.0f);
    y1 = fmaxf(y1, 0.0f);
    float x2 = fminf(pcx + 0.5f * pw, IMG_W);
    float y2 = fminf(pcy + 0.5f * ph, IMG_H);
    obox[a] = make_float4(x1, y1, x2, y2);

    float s    = scb[a];
    bool valid = (s > 0.05f);
    localcnt  += valid ? 1 : 0;
    float key  = valid ? -s : __int_as_float(0x7f800000);  // +inf if invalid
    skey[a] = ((unsigned long long)enc_f32(key) << 32) | (unsigned)a;
  }
  atomicAdd(&cntS, localcnt);
  __syncthreads();

  // stable bitonic sort ascending (unique keys: idx in low 32 bits)
  for (int k = 2; k <= NA; k <<= 1) {
    for (int j = k >> 1; j > 0; j >>= 1) {
      for (int m = tid; m < NA; m += 256) {
        int mx = m ^ j;
        if (mx > m) {
          unsigned long long va = skey[m];
          unsigned long long vb = skey[mx];
          bool up = ((m & k) == 0);
          if ((va > vb) == up) { skey[m] = vb; skey[mx] = va; }
        }
      }
      __syncthreads();
    }
  }

  unsigned long long* pk = skeyG + (size_t)bc * NA;
  float4* pb = sboxG + (size_t)bc * NA;
#pragma unroll
  for (int m = 0; m < 4; ++m) {
    int r = tid + m * 256;
    unsigned long long kv = skey[r];
    int orig = (int)(unsigned)kv;
    pk[r] = kv;
    pb[r] = obox[orig];
  }
  if (tid == 0) nvalidG[bc] = cntS;
}

// ---------------------------------------------------------------------------
// K2: TRANSPOSED suppression bitmask  T[p][c][j], bit i of T[p][c][j] =
//     "sorted row c*64+i suppresses sorted column j"  (only i with c*64+i < j).
// Grid (10, NP) x 256. Each wave = task (c, g): row-chunk c (serial, LDS
// broadcast), columns j = 256g+64k+lane (register-cached, k=0..3).
// Lanes own columns -> output is naturally transposed, stores coalesced.
// IoU math bit-identical to the verified r3/r4 predicate (all ops commutative):
//   RN(inter/un) > 0.5  <=>  (2*inter - un) > un * 2^-24
// ---------------------------------------------------------------------------
__global__ __launch_bounds__(256) void mask_kernel(
    const float4* __restrict__ sboxG,
    const int* __restrict__ nvalidG,
    unsigned long long* __restrict__ maskT)   // (NP, NWORD, NA)
{
#pragma clang fp contract(off)
  const int p      = blockIdx.y;
  const int q      = blockIdx.x;       // 0..9
  const int tid    = threadIdx.x;
  const int waveId = tid >> 6;
  const int lane   = tid & 63;

  __shared__ __align__(16) float4 sb[NA];   // 16 KB
  __shared__ float sa[NA];                  // 4 KB

  const float4* pb = sboxG + (size_t)p * NA;
  for (int r = tid; r < NA; r += 256) {
    float4 bx = pb[r];
    sb[r] = bx;
    sa[r] = (bx.z - bx.x) * (bx.w - bx.y);
  }
  const int nv = nvalidG[p];
  __syncthreads();

  // task t=0..39 -> (c,g), g >= c>>2:
  //   c=0..3: g=0..3 | c=4..7: g=1..3 | c=8..11: g=2..3 | c=12..15: g=3
  const int t = q * 4 + waveId;
  int c, g;
  if (t < 16)      { c = t >> 2;            g = t & 3; }
  else if (t < 28) { int i = t - 16; c = 4 + i / 3;     g = 1 + i % 3; }
  else if (t < 36) { int i = t - 28; c = 8 + (i >> 1);  g = 2 + (i & 1); }
  else             { int i = t - 36; c = 12 + i;        g = 3; }

  if (64 * c >= nv) return;   // plane never read by K3

  // register-cache 4 column boxes
  float4 cb[4]; float ca[4];
  unsigned long long bits[4] = {0ull, 0ull, 0ull, 0ull};
#pragma unroll
  for (int k = 0; k < 4; ++k) {
    int j = 256 * g + 64 * k + lane;
    cb[k] = sb[j];
    ca[k] = sa[j];
  }

  const int rbase = 64 * c;
#pragma unroll 8
  for (int i2 = 0; i2 < 64; ++i2) {
    float4 br = sb[rbase + i2];    // wave-broadcast
    float  ar = sa[rbase + i2];
#pragma unroll
    for (int k = 0; k < 4; ++k) {
      float ix1 = fmaxf(br.x, cb[k].x);
      float iy1 = fmaxf(br.y, cb[k].y);
      float ix2 = fminf(br.z, cb[k].z);
      float iy2 = fminf(br.w, cb[k].w);
      float inter = fmaxf(ix2 - ix1, 0.0f) * fmaxf(iy2 - iy1, 0.0f);
      float un = fmaxf((ar + ca[k]) - inter, 1e-9f);
      bool sup = ((inter + inter) - un) > un * 5.9604644775390625e-8f;
      bits[k] |= sup ? (1ull << i2) : 0ull;
    }
  }

  unsigned long long* pPlane = maskT + ((size_t)p * NWORD + c) * NA;
#pragma unroll
  for (int k = 0; k < 4; ++k) {
    int jb = 256 * g + 64 * k;
    if (jb < 64 * c) continue;           // dead block (j < rows), never read
    unsigned long long bv = bits[k];
    if (jb == 64 * c)                    // diagonal block: need i < lane
      bv &= (1ull << lane) - 1ull;       // lane 0 -> 0
    pPlane[jb + lane] = bv;              // coalesced 512B store
  }
}

// ---------------------------------------------------------------------------
// K3: greedy scan, one wave per problem. No shfl/bpermute in the serial
// chain: per-lane suppressor word + ballot-combined fixed-point rounds.
// ---------------------------------------------------------------------------
__global__ __launch_bounds__(64) void scan_kernel(
    const unsigned long long* __restrict__ skeyG,
    const float4* __restrict__ sboxG,
    const unsigned long long* __restrict__ maskT,   // (NP, NWORD, NA)
    const int* __restrict__ nvalidG,
    float* __restrict__ out)              // (NP, NA, 5)
{
  const int p    = blockIdx.x;
  const int lane = threadIdx.x;

  __shared__ unsigned long long keptS[NWORD];
  __shared__ __align__(16) float outAll[NA * 5];   // 20 KB

  if (lane < NWORD) keptS[lane] = 0ull;

  const int nv = nvalidG[p];
  const int nchunk = (nv + 63) >> 6;
  const unsigned long long* pT = maskT + (size_t)p * NWORD * NA;

  unsigned suppFut = 0u;   // bit w: sorted row w*64+lane pre-suppressed
  unsigned long long diag = 0ull;
  if (nchunk > 0) diag = pT[lane];       // T[0][0*64+lane]

  for (int c = 0; c < nchunk; ++c) {
    // issue all loads up front (independent of this chunk's decisions)
    unsigned long long fut[NWORD];
#pragma unroll
    for (int w = 0; w < NWORD; ++w)
      fut[w] = pT[(size_t)c * NA + w * 64 + lane];   // w<=c lanes unused
    unsigned long long diagN = 0ull;
    if (c + 1 < nchunk) diagN = pT[(size_t)(c + 1) * NA + (c + 1) * 64 + lane];

    // fixed-point decided loop (ballots only; no bpermute)
    unsigned long long valid = __ballot(c * 64 + lane < nv);
    unsigned long long S     = __ballot((suppFut >> c) & 1u);
    unsigned long long K  = 0ull;
    unsigned long long Dd = (~valid) | S;
    for (int round = 0; round < 64; ++round) {
      unsigned long long und = ~Dd;
      if (und == 0ull) break;                        // wave-uniform
      bool me_und   = (und >> lane) & 1ull;
      bool blocked  = (diag & (K | und)) != 0ull;    // kept or undecided suppressor
      bool isSupp   = (diag & K) != 0ull;
      unsigned long long kb  = __ballot(me_und && !blocked);
      unsigned long long sbm = __ballot(me_und && isSupp);
      K  |= kb;
      Dd |= kb | sbm;
    }
    if (lane == 0) keptS[c] = K;

    // per-lane local future-suppression update (no cross-lane traffic)
#pragma unroll
    for (int w = 0; w < NWORD; ++w)
      if (w > c) suppFut |= ((fut[w] & K) != 0ull) ? (1u << w) : 0u;

    diag = diagN;
  }
  __syncthreads();   // keptS visible

  // stage output in original anchor order (verified r4 path)
  const unsigned long long* pk = skeyG + (size_t)p * NA;
  const float4* pb = sboxG + (size_t)p * NA;
#pragma unroll 4
  for (int it = 0; it < NWORD; ++it) {
    int r = it * 64 + lane;
    unsigned long long kv = pk[r];
    float4 bx = pb[r];
    int orig = (int)(unsigned)kv;
    bool kp = (keptS[it] >> lane) & 1ull;
    float sc = 0.0f;
    float4 ob = make_float4(0.0f, 0.0f, 0.0f, 0.0f);
    if (kp) {
      sc = -__uint_as_float(~(unsigned)(kv >> 32));  // exact original score
      ob = bx;
    }
    float* oa = outAll + (size_t)orig * 5;
    oa[0] = sc; oa[1] = ob.x; oa[2] = ob.y; oa[3] = ob.z; oa[4] = ob.w;
  }
  __syncthreads();

  float4* og = (float4*)(out + (size_t)p * NA * 5);
  const float4* ol = (const float4*)outAll;
  for (int t4 = lane; t4 < (NA * 5) / 4; t4 += 64) og[t4] = ol[t4];
}

// ---------------------------------------------------------------------------
// Fallback: round-1 monolithic kernel (used only if ws_size is too small)
// ---------------------------------------------------------------------------
__global__ __launch_bounds__(256) void nms_mono_kernel(
    const float* __restrict__ cls_pred,
    const float* __restrict__ reg_pred,
    const float* __restrict__ anchors,
    float* __restrict__ out)
{
#pragma clang fp contract(off)
  const int bc  = blockIdx.x;
  const int b   = bc / NCLS;
  const int tid = threadIdx.x;
  const int BNT = 256, BPT = 4;

  __shared__ __align__(16) unsigned char smem[49152];
  float4*             obox  = (float4*)(smem);
  float4*             sbox  = (float4*)(smem + 16384);
  unsigned long long* skey  = (unsigned long long*)(smem + 32768);
  float*              sarea = (float*)(smem + 40960);
  int*                keepL = (int*)(smem + 45056);

  const float* regb = reg_pred + (size_t)b * 4 * NA;
  const float* scb  = cls_pred + (size_t)bc * NA;
  for (int a = tid; a < NA; a += BNT) {
    float4 an = ((const float4*)anchors)[a];
    float w  = an.z - an.x;
    float h  = an.w - an.y;
    float cx = an.x + 0.5f * w;
    float cy = an.y + 0.5f * h;
    float dx = regb[0 * NA + a] * 0.1f;
    float dy = regb[1 * NA + a] * 0.1f;
    float dw = regb[2 * NA + a] * 0.2f;
    float dh = regb[3 * NA + a] * 0.2f;
    float pcx = cx + dx * w;
    float pcy = cy + dy * h;
    float pw  = expf(dw) * w;
    float ph  = expf(dh) * h;
    float x1 = fmaxf(fmaxf(pcx - 0.5f * pw, 0.0f), 0.0f);
    float y1 = fmaxf(pcy - 0.5f * ph, 0.0f);
    float x2 = fminf(pcx + 0.5f * pw, IMG_W);
    float y2 = fminf(pcy + 0.5f * ph, IMG_H);
    obox[a] = make_float4(x1, y1, x2, y2);
    float s   = scb[a];
    float key = (s > 0.05f) ? -s : __int_as_float(0x7f800000);
    skey[a] = ((unsigned long long)enc_f32(key) << 32) | (unsigned)a;
  }
  __syncthreads();
  for (int k = 2; k <= NA; k <<= 1) {
    for (int j = k >> 1; j > 0; j >>= 1) {
      for (int m = tid; m < NA; m += BNT) {
        int mx = m ^ j;
        if (mx > m) {
          unsigned long long va = skey[m];
          unsigned long long vb = skey[mx];
          bool up = ((m & k) == 0);
          if ((va > vb) == up) { skey[m] = vb; skey[mx] = va; }
        }
      }
      __syncthreads();
    }
  }
  float4 bj[4]; float aj[4]; int kj[4];
#pragma unroll
  for (int m = 0; m < BPT; ++m) {
    int r = tid + m * BNT;
    unsigned long long kv = skey[r];
    int orig = (int)(unsigned)kv;
    float4 bx = obox[orig];
    sbox[r] = bx;
    float ar = (bx.z - bx.x) * (bx.w - bx.y);
    sarea[r] = ar;
    int kp = ((unsigned)(kv >> 32) != 0xFF800000u) ? 1 : 0;
    keepL[r] = kp;
    bj[m] = bx; aj[m] = ar; kj[m] = kp;
  }
  for (int i = 0; i < NA; ++i) {
    __syncthreads();
    if (keepL[i] == 0) continue;
    float4 bi = sbox[i];
    float  ai = sarea[i];
#pragma unroll
    for (int m = 0; m < BPT; ++m) {
      int j = tid + m * BNT;
      if (j > i && kj[m]) {
        float ix1 = fmaxf(bi.x, bj[m].x);
        float iy1 = fmaxf(bi.y, bj[m].y);
        float ix2 = fminf(bi.z, bj[m].z);
        float iy2 = fminf(bi.w, bj[m].w);
        float inter = fmaxf(ix2 - ix1, 0.0f) * fmaxf(iy2 - iy1, 0.0f);
        float un = fmaxf(ai + aj[m] - inter, 1e-9f);
        if (inter / un > 0.5f) { kj[m] = 0; keepL[j] = 0; }
      }
    }
  }
  __syncthreads();
  float4* outbox = obox;
  float*  outsc  = sarea;
#pragma unroll
  for (int m = 0; m < BPT; ++m) {
    int r = tid + m * BNT;
    unsigned long long kv = skey[r];
    int orig = (int)(unsigned)kv;
    float  sc = 0.0f;
    float4 bx = make_float4(0.0f, 0.0f, 0.0f, 0.0f);
    if (kj[m]) {
      sc = -__uint_as_float(~(unsigned)(kv >> 32));
      bx = sbox[r];
    }
    outsc[orig]  = sc;
    outbox[orig] = bx;
  }
  __syncthreads();
  float* ob = out + (size_t)bc * NA * 5;
  for (int a = tid; a < NA; a += BNT) {
    float4 bx = outbox[a];
    float* o = ob + (size_t)a * 5;
    o[0] = outsc[a]; o[1] = bx.x; o[2] = bx.y; o[3] = bx.z; o[4] = bx.w;
  }
}

// ---------------------------------------------------------------------------
extern "C" void kernel_launch(void* const* d_in, const int* in_sizes, int n_in,
                              void* d_out, int out_size, void* d_ws, size_t ws_size,
                              hipStream_t stream) {
  const float* cls = (const float*)d_in[1];
  const float* reg = (const float*)d_in[2];
  const float* anc = (const float*)d_in[3];
  float* out = (float*)d_out;

  // workspace layout (256B-aligned blocks)
  const size_t off_key  = 0;                                    // NP*NA*8
  const size_t off_box  = off_key + (size_t)NP * NA * 8;        // NP*NA*16
  const size_t off_mask = off_box + (size_t)NP * NA * 16;       // NP*NWORD*NA*8
  const size_t off_nv   = off_mask + (size_t)NP * NWORD * NA * 8;
  const size_t need     = off_nv + (size_t)NP * sizeof(int);

  if (ws_size < need) {
    nms_mono_kernel<<<dim3(NP), dim3(256), 0, stream>>>(cls, reg, anc, out);
    return;
  }

  char* ws = (char*)d_ws;
  unsigned long long* skeyG = (unsigned long long*)(ws + off_key);
  float4*             sboxG = (float4*)(ws + off_box);
  unsigned long long* maskT = (unsigned long long*)(ws + off_mask);
  int*                nvG   = (int*)(ws + off_nv);

  decode_sort_kernel<<<dim3(NP), dim3(256), 0, stream>>>(cls, reg, anc, skeyG, sboxG, nvG);
  mask_kernel<<<dim3(10, NP), dim3(256), 0, stream>>>(sboxG, nvG, maskT);
  scan_kernel<<<dim3(NP), dim3(64), 0, stream>>>(skeyG, sboxG, maskT, nvG, out);
}

// Round 6
// 217.900 us; speedup vs baseline: 1.5823x; 1.0921x over previous
//
#include <hip/hip_runtime.h>
#include <stdint.h>

// Problem constants (fixed by setup_inputs): B=2, C=80, A=1024, H=W=2048
#define BATCH 2
#define NCLS 80
#define NP (BATCH * NCLS)   // 160 independent NMS problems
#define NA 1024
#define NWORD 16            // NA/64
#define IMG_W 2048.0f
#define IMG_H 2048.0f

// monotone float -> uint mapping (ascending uint order == ascending float order)
__device__ __forceinline__ unsigned enc_f32(float f) {
  unsigned u = __float_as_uint(f);
  return (u & 0x80000000u) ? ~u : (u | 0x80000000u);
}

// ---------------------------------------------------------------------------
// K1: decode boxes, build stable sort keys, bitonic sort (verified r2-r5).
// ---------------------------------------------------------------------------
__global__ __launch_bounds__(256) void decode_sort_kernel(
    const float* __restrict__ cls_pred,   // (B, C, A)
    const float* __restrict__ reg_pred,   // (B, 4, A)
    const float* __restrict__ anchors,    // (A, 4)
    unsigned long long* __restrict__ skeyG,  // (NP, NA)
    float4* __restrict__ sboxG,              // (NP, NA)
    int* __restrict__ nvalidG)               // (NP)
{
#pragma clang fp contract(off)
  const int bc  = blockIdx.x;
  const int b   = bc / NCLS;
  const int tid = threadIdx.x;

  __shared__ __align__(16) float4 obox[NA];            // 16 KB
  __shared__ unsigned long long skey[NA];              // 8 KB
  __shared__ int cntS;

  if (tid == 0) cntS = 0;
  __syncthreads();

  const float* regb = reg_pred + (size_t)b * 4 * NA;
  const float* scb  = cls_pred + (size_t)bc * NA;
  int localcnt = 0;
  for (int a = tid; a < NA; a += 256) {
    float4 an = ((const float4*)anchors)[a];
    float w  = an.z - an.x;
    float h  = an.w - an.y;
    float cx = an.x + 0.5f * w;
    float cy = an.y + 0.5f * h;
    float dx = regb[0 * NA + a] * 0.1f;
    float dy = regb[1 * NA + a] * 0.1f;
    float dw = regb[2 * NA + a] * 0.2f;
    float dh = regb[3 * NA + a] * 0.2f;
    float pcx = cx + dx * w;
    float pcy = cy + dy * h;
    float pw  = expf(dw) * w;
    float ph  = expf(dh) * h;
    float x1 = fmaxf(pcx - 0.5f * pw, 0.0f);
    float y1 = pcy - 0.5f * ph;
    x1 = fmaxf(x1, 0.0f);
    y1 = fmaxf(y1, 0.0f);
    float x2 = fminf(pcx + 0.5f * pw, IMG_W);
    float y2 = fminf(pcy + 0.5f * ph, IMG_H);
    obox[a] = make_float4(x1, y1, x2, y2);

    float s    = scb[a];
    bool valid = (s > 0.05f);
    localcnt  += valid ? 1 : 0;
    float key  = valid ? -s : __int_as_float(0x7f800000);  // +inf if invalid
    skey[a] = ((unsigned long long)enc_f32(key) << 32) | (unsigned)a;
  }
  atomicAdd(&cntS, localcnt);
  __syncthreads();

  // stable bitonic sort ascending (unique keys: idx in low 32 bits)
  for (int k = 2; k <= NA; k <<= 1) {
    for (int j = k >> 1; j > 0; j >>= 1) {
      for (int m = tid; m < NA; m += 256) {
        int mx = m ^ j;
        if (mx > m) {
          unsigned long long va = skey[m];
          unsigned long long vb = skey[mx];
          bool up = ((m & k) == 0);
          if ((va > vb) == up) { skey[m] = vb; skey[mx] = va; }
        }
      }
      __syncthreads();
    }
  }

  unsigned long long* pk = skeyG + (size_t)bc * NA;
  float4* pb = sboxG + (size_t)bc * NA;
#pragma unroll
  for (int m = 0; m < 4; ++m) {
    int r = tid + m * 256;
    unsigned long long kv = skey[r];
    int orig = (int)(unsigned)kv;
    pk[r] = kv;
    pb[r] = obox[orig];
  }
  if (tid == 0) nvalidG[bc] = cntS;
}

// ---------------------------------------------------------------------------
// K-W: per-batch symmetric suppression matrix in ORIGINAL anchor order.
//   W[b][i][kw] bit jj = predicate(IoU(box_i, box_{kw*64+jj}) > 0.5)
// Boxes depend only on (reg_pred[b], anchors) -> shared by all 80 classes.
// Decode code bit-identical to K1; predicate bit-identical to verified r3-r5:
//   RN(inter/un) > 0.5  <=>  (2*inter - un) > un * 2^-24   (ops commutative)
// Grid (16, BATCH) x 256: block handles rows rblk*64..+63; lane = row,
// wave handles 4 of 16 column-words (column reads are wave-broadcast).
// ---------------------------------------------------------------------------
__global__ __launch_bounds__(256) void build_w_kernel(
    const float* __restrict__ reg_pred,   // (B, 4, A)
    const float* __restrict__ anchors,    // (A, 4)
    unsigned long long* __restrict__ W)   // (B, NA, NWORD)
{
#pragma clang fp contract(off)
  const int b    = blockIdx.y;
  const int rblk = blockIdx.x;           // 0..15
  const int tid  = threadIdx.x;
  const int lane = tid & 63;
  const int wq   = tid >> 6;             // wave id 0..3

  __shared__ __align__(16) float4 sb[NA];   // 16 KB
  __shared__ float sa[NA];                  // 4 KB

  const float* regb = reg_pred + (size_t)b * 4 * NA;
  for (int a = tid; a < NA; a += 256) {
    float4 an = ((const float4*)anchors)[a];
    float w  = an.z - an.x;
    float h  = an.w - an.y;
    float cx = an.x + 0.5f * w;
    float cy = an.y + 0.5f * h;
    float dx = regb[0 * NA + a] * 0.1f;
    float dy = regb[1 * NA + a] * 0.1f;
    float dw = regb[2 * NA + a] * 0.2f;
    float dh = regb[3 * NA + a] * 0.2f;
    float pcx = cx + dx * w;
    float pcy = cy + dy * h;
    float pw  = expf(dw) * w;
    float ph  = expf(dh) * h;
    float x1 = fmaxf(pcx - 0.5f * pw, 0.0f);
    float y1 = pcy - 0.5f * ph;
    x1 = fmaxf(x1, 0.0f);
    y1 = fmaxf(y1, 0.0f);
    float x2 = fminf(pcx + 0.5f * pw, IMG_W);
    float y2 = fminf(pcy + 0.5f * ph, IMG_H);
    float4 bx = make_float4(x1, y1, x2, y2);
    sb[a] = bx;
    sa[a] = (bx.z - bx.x) * (bx.w - bx.y);
  }
  __syncthreads();

  const int r = rblk * 64 + lane;        // this lane's row
  float4 br = sb[r];
  float  ar = sa[r];
  unsigned long long* wrow = W + ((size_t)b * NA + r) * NWORD;

#pragma unroll
  for (int k2 = 0; k2 < 4; ++k2) {
    const int kw = wq * 4 + k2;          // word index 0..15
    const int jbase = kw * 64;
    unsigned long long bits = 0ull;
#pragma unroll 8
    for (int jj = 0; jj < 64; ++jj) {
      float4 bj = sb[jbase + jj];        // wave-broadcast
      float  aj = sa[jbase + jj];
      float ix1 = fmaxf(br.x, bj.x);
      float iy1 = fmaxf(br.y, bj.y);
      float ix2 = fminf(br.z, bj.z);
      float iy2 = fminf(br.w, bj.w);
      float inter = fmaxf(ix2 - ix1, 0.0f) * fmaxf(iy2 - iy1, 0.0f);
      float un = fmaxf((ar + aj) - inter, 1e-9f);
      bool sup = ((inter + inter) - un) > un * 5.9604644775390625e-8f;
      bits |= sup ? (1ull << jj) : 0ull;
    }
    wrow[kw] = bits;
  }
}

// ---------------------------------------------------------------------------
// K3: greedy scan with on-the-fly permutation gather from the shared W.
// One wave per problem. Per chunk c (64 sorted boxes):
//   - load the 64 chunk rows W[o(c*64+si)] into LDS (chunk's rows == its
//     columns' rows, by symmetry of W)
//   - presupp(lane) = (own row & K_orig) != 0        [replaces r5 fut words]
//   - diag(lane) bit si = W[o(si)][o(lane col)]
//       = bit (o_mine&63) of word (o_mine>>6) of LDS row si  [symmetry]
//   - verified r5 fixed-point ballot loop (unchanged)
//   - kept lanes atomicOr their orig bit into K_orig
// ---------------------------------------------------------------------------
__global__ __launch_bounds__(64) void scan_kernel(
    const unsigned long long* __restrict__ skeyG,
    const float4* __restrict__ sboxG,
    const unsigned long long* __restrict__ W,     // (B, NA, NWORD)
    const int* __restrict__ nvalidG,
    float* __restrict__ out)              // (NP, NA, 5)
{
  const int p    = blockIdx.x;
  const int b    = p / NCLS;
  const int lane = threadIdx.x;

  __shared__ unsigned long long rowsL[64 * 17];    // 8704 B (136B row stride)
  __shared__ int oL[NA];                           // 4 KB sorted->orig map
  __shared__ unsigned long long KorigL[NWORD];     // kept set, orig space
  __shared__ unsigned long long keptS[NWORD];
  __shared__ __align__(16) float outAll[NA * 5];   // 20 KB

  if (lane < NWORD) { KorigL[lane] = 0ull; keptS[lane] = 0ull; }

  const int nv = nvalidG[p];
  const int nchunk = (nv + 63) >> 6;
  const unsigned long long* pk = skeyG + (size_t)p * NA;
  const unsigned long long* Wb = W + (size_t)b * NA * NWORD;

  // load all sorted->orig indices
#pragma unroll
  for (int it = 0; it < NWORD; ++it) {
    int r = it * 64 + lane;
    oL[r] = (int)(unsigned)pk[r];
  }
  __syncthreads();

  for (int c = 0; c < nchunk; ++c) {
    // 1. stage chunk rows: row si = W[oL[c*64+si]] (16 iters, 4 rows each)
#pragma unroll 4
    for (int t = 0; t < 16; ++t) {
      int si = t * 4 + (lane >> 4);
      int orow = oL[c * 64 + si];
      rowsL[si * 17 + (lane & 15)] = Wb[(size_t)orow * NWORD + (lane & 15)];
    }
    __syncthreads();

    const int sMine = c * 64 + lane;
    const int oMine = oL[sMine];

    // 2. pre-suppressed by earlier-chunk kept boxes
    unsigned long long pp = 0ull;
#pragma unroll
    for (int k = 0; k < NWORD; ++k)
      pp |= rowsL[lane * 17 + k] & KorigL[k];

    // 3. within-chunk diag gather (broadcast reads, conflict-free)
    const int wsel = oMine >> 6;
    const int bsel = oMine & 63;
    unsigned long long diag = 0ull;
#pragma unroll 16
    for (int si = 0; si < 64; ++si) {
      unsigned long long rw = rowsL[si * 17 + wsel];
      diag |= ((rw >> bsel) & 1ull) << si;
    }
    diag &= (1ull << lane) - 1ull;       // only si < lane (lane 0 -> 0)

    // 4. fixed-point decided loop (verified r5)
    unsigned long long valid = __ballot(sMine < nv);
    unsigned long long S     = __ballot(pp != 0ull);
    unsigned long long K  = 0ull;
    unsigned long long Dd = (~valid) | S;
    for (int round = 0; round < 64; ++round) {
      unsigned long long und = ~Dd;
      if (und == 0ull) break;                        // wave-uniform
      bool me_und  = (und >> lane) & 1ull;
      bool blocked = (diag & (K | und)) != 0ull;
      bool isSupp  = (diag & K) != 0ull;
      unsigned long long kb  = __ballot(me_und && !blocked);
      unsigned long long sbm = __ballot(me_und && isSupp);
      K  |= kb;
      Dd |= kb | sbm;
    }
    if (lane == 0) keptS[c] = K;

    // 5. add kept boxes to K_orig (orig space)
    if ((K >> lane) & 1ull)
      atomicOr(&KorigL[oMine >> 6], 1ull << (oMine & 63));
    __syncthreads();
  }
  __syncthreads();   // keptS visible

  // stage output in original anchor order (verified r4/r5 path)
  const float4* pb = sboxG + (size_t)p * NA;
#pragma unroll 4
  for (int it = 0; it < NWORD; ++it) {
    int r = it * 64 + lane;
    unsigned long long kv = pk[r];
    float4 bx = pb[r];
    int orig = (int)(unsigned)kv;
    bool kp = (keptS[it] >> lane) & 1ull;
    float sc = 0.0f;
    float4 ob = make_float4(0.0f, 0.0f, 0.0f, 0.0f);
    if (kp) {
      sc = -__uint_as_float(~(unsigned)(kv >> 32));  // exact original score
      ob = bx;
    }
    float* oa = outAll + (size_t)orig * 5;
    oa[0] = sc; oa[1] = ob.x; oa[2] = ob.y; oa[3] = ob.z; oa[4] = ob.w;
  }
  __syncthreads();

  float4* og = (float4*)(out + (size_t)p * NA * 5);
  const float4* ol = (const float4*)outAll;
  for (int t4 = lane; t4 < (NA * 5) / 4; t4 += 64) og[t4] = ol[t4];
}

// ---------------------------------------------------------------------------
// Fallback: round-1 monolithic kernel (used only if ws_size is too small)
// ---------------------------------------------------------------------------
__global__ __launch_bounds__(256) void nms_mono_kernel(
    const float* __restrict__ cls_pred,
    const float* __restrict__ reg_pred,
    const float* __restrict__ anchors,
    float* __restrict__ out)
{
#pragma clang fp contract(off)
  const int bc  = blockIdx.x;
  const int b   = bc / NCLS;
  const int tid = threadIdx.x;
  const int BNT = 256, BPT = 4;

  __shared__ __align__(16) unsigned char smem[49152];
  float4*             obox  = (float4*)(smem);
  float4*             sbox  = (float4*)(smem + 16384);
  unsigned long long* skey  = (unsigned long long*)(smem + 32768);
  float*              sarea = (float*)(smem + 40960);
  int*                keepL = (int*)(smem + 45056);

  const float* regb = reg_pred + (size_t)b * 4 * NA;
  const float* scb  = cls_pred + (size_t)bc * NA;
  for (int a = tid; a < NA; a += BNT) {
    float4 an = ((const float4*)anchors)[a];
    float w  = an.z - an.x;
    float h  = an.w - an.y;
    float cx = an.x + 0.5f * w;
    float cy = an.y + 0.5f * h;
    float dx = regb[0 * NA + a] * 0.1f;
    float dy = regb[1 * NA + a] * 0.1f;
    float dw = regb[2 * NA + a] * 0.2f;
    float dh = regb[3 * NA + a] * 0.2f;
    float pcx = cx + dx * w;
    float pcy = cy + dy * h;
    float pw  = expf(dw) * w;
    float ph  = expf(dh) * h;
    float x1 = fmaxf(fmaxf(pcx - 0.5f * pw, 0.0f), 0.0f);
    float y1 = fmaxf(pcy - 0.5f * ph, 0.0f);
    float x2 = fminf(pcx + 0.5f * pw, IMG_W);
    float y2 = fminf(pcy + 0.5f * ph, IMG_H);
    obox[a] = make_float4(x1, y1, x2, y2);
    float s   = scb[a];
    float key = (s > 0.05f) ? -s : __int_as_float(0x7f800000);
    skey[a] = ((unsigned long long)enc_f32(key) << 32) | (unsigned)a;
  }
  __syncthreads();
  for (int k = 2; k <= NA; k <<= 1) {
    for (int j = k >> 1; j > 0; j >>= 1) {
      for (int m = tid; m < NA; m += BNT) {
        int mx = m ^ j;
        if (mx > m) {
          unsigned long long va = skey[m];
          unsigned long long vb = skey[mx];
          bool up = ((m & k) == 0);
          if ((va > vb) == up) { skey[m] = vb; skey[mx] = va; }
        }
      }
      __syncthreads();
    }
  }
  float4 bj[4]; float aj[4]; int kj[4];
#pragma unroll
  for (int m = 0; m < BPT; ++m) {
    int r = tid + m * BNT;
    unsigned long long kv = skey[r];
    int orig = (int)(unsigned)kv;
    float4 bx = obox[orig];
    sbox[r] = bx;
    float ar = (bx.z - bx.x) * (bx.w - bx.y);
    sarea[r] = ar;
    int kp = ((unsigned)(kv >> 32) != 0xFF800000u) ? 1 : 0;
    keepL[r] = kp;
    bj[m] = bx; aj[m] = ar; kj[m] = kp;
  }
  for (int i = 0; i < NA; ++i) {
    __syncthreads();
    if (keepL[i] == 0) continue;
    float4 bi = sbox[i];
    float  ai = sarea[i];
#pragma unroll
    for (int m = 0; m < BPT; ++m) {
      int j = tid + m * BNT;
      if (j > i && kj[m]) {
        float ix1 = fmaxf(bi.x, bj[m].x);
        float iy1 = fmaxf(bi.y, bj[m].y);
        float ix2 = fminf(bi.z, bj[m].z);
        float iy2 = fminf(bi.w, bj[m].w);
        float inter = fmaxf(ix2 - ix1, 0.0f) * fmaxf(iy2 - iy1, 0.0f);
        float un = fmaxf(ai + aj[m] - inter, 1e-9f);
        if (inter / un > 0.5f) { kj[m] = 0; keepL[j] = 0; }
      }
    }
  }
  __syncthreads();
  float4* outbox = obox;
  float*  outsc  = sarea;
#pragma unroll
  for (int m = 0; m < BPT; ++m) {
    int r = tid + m * BNT;
    unsigned long long kv = skey[r];
    int orig = (int)(unsigned)kv;
    float  sc = 0.0f;
    float4 bx = make_float4(0.0f, 0.0f, 0.0f, 0.0f);
    if (kj[m]) {
      sc = -__uint_as_float(~(unsigned)(kv >> 32));
      bx = sbox[r];
    }
    outsc[orig]  = sc;
    outbox[orig] = bx;
  }
  __syncthreads();
  float* ob = out + (size_t)bc * NA * 5;
  for (int a = tid; a < NA; a += BNT) {
    float4 bx = outbox[a];
    float* o = ob + (size_t)a * 5;
    o[0] = outsc[a]; o[1] = bx.x; o[2] = bx.y; o[3] = bx.z; o[4] = bx.w;
  }
}

// ---------------------------------------------------------------------------
extern "C" void kernel_launch(void* const* d_in, const int* in_sizes, int n_in,
                              void* d_out, int out_size, void* d_ws, size_t ws_size,
                              hipStream_t stream) {
  const float* cls = (const float*)d_in[1];
  const float* reg = (const float*)d_in[2];
  const float* anc = (const float*)d_in[3];
  float* out = (float*)d_out;

  // workspace layout (256B-aligned blocks)
  const size_t off_key = 0;                                    // NP*NA*8
  const size_t off_box = off_key + (size_t)NP * NA * 8;        // NP*NA*16
  const size_t off_w   = off_box + (size_t)NP * NA * 16;       // B*NA*NWORD*8
  const size_t off_nv  = off_w + (size_t)BATCH * NA * NWORD * 8;
  const size_t need    = off_nv + (size_t)NP * sizeof(int);

  if (ws_size < need) {
    nms_mono_kernel<<<dim3(NP), dim3(256), 0, stream>>>(cls, reg, anc, out);
    return;
  }

  char* ws = (char*)d_ws;
  unsigned long long* skeyG = (unsigned long long*)(ws + off_key);
  float4*             sboxG = (float4*)(ws + off_box);
  unsigned long long* Wm    = (unsigned long long*)(ws + off_w);
  int*                nvG   = (int*)(ws + off_nv);

  build_w_kernel<<<dim3(NWORD, BATCH), dim3(256), 0, stream>>>(reg, anc, Wm);
  decode_sort_kernel<<<dim3(NP), dim3(256), 0, stream>>>(cls, reg, anc, skeyG, sboxG, nvG);
  scan_kernel<<<dim3(NP), dim3(64), 0, stream>>>(skeyG, sboxG, Wm, nvG, out);
}

// Round 7
// 189.788 us; speedup vs baseline: 1.8167x; 1.1481x over previous
//
#include <hip/hip_runtime.h>
#include <stdint.h>

// Problem constants (fixed by setup_inputs): B=2, C=80, A=1024, H=W=2048
#define BATCH 2
#define NCLS 80
#define NP (BATCH * NCLS)   // 160 independent NMS problems
#define NA 1024
#define NWORD 16            // NA/64
#define IMG_W 2048.0f
#define IMG_H 2048.0f

// monotone float -> uint mapping (ascending uint order == ascending float order)
__device__ __forceinline__ unsigned enc_f32(float f) {
  unsigned u = __float_as_uint(f);
  return (u & 0x80000000u) ? ~u : (u | 0x80000000u);
}

// ---------------------------------------------------------------------------
// K1 (merged): blocks 0..NP-1 = decode+sort (verified r2-r6);
//              blocks NP..NP+31 = per-batch symmetric W matrix (verified r6).
// The two halves touch disjoint outputs and share no state.
// ---------------------------------------------------------------------------
__global__ __launch_bounds__(256) void prep_kernel(
    const float* __restrict__ cls_pred,   // (B, C, A)
    const float* __restrict__ reg_pred,   // (B, 4, A)
    const float* __restrict__ anchors,    // (A, 4)
    unsigned long long* __restrict__ skeyG,  // (NP, NA)
    float4* __restrict__ sboxG,              // (NP, NA)
    int* __restrict__ nvalidG,               // (NP)
    unsigned long long* __restrict__ W)      // (B, NA, NWORD)
{
#pragma clang fp contract(off)
  const int tid = threadIdx.x;
  __shared__ __align__(16) unsigned char smem[24832];

  if (blockIdx.x < NP) {
    // ================= decode + stable bitonic sort =================
    const int bc = blockIdx.x;
    const int b  = bc / NCLS;
    float4*             obox = (float4*)(smem);                  // 16 KB
    unsigned long long* skey = (unsigned long long*)(smem + 16384); // 8 KB
    int*                cntS = (int*)(smem + 24576);

    if (tid == 0) *cntS = 0;
    __syncthreads();

    const float* regb = reg_pred + (size_t)b * 4 * NA;
    const float* scb  = cls_pred + (size_t)bc * NA;
    int localcnt = 0;
    for (int a = tid; a < NA; a += 256) {
      float4 an = ((const float4*)anchors)[a];
      float w  = an.z - an.x;
      float h  = an.w - an.y;
      float cx = an.x + 0.5f * w;
      float cy = an.y + 0.5f * h;
      float dx = regb[0 * NA + a] * 0.1f;
      float dy = regb[1 * NA + a] * 0.1f;
      float dw = regb[2 * NA + a] * 0.2f;
      float dh = regb[3 * NA + a] * 0.2f;
      float pcx = cx + dx * w;
      float pcy = cy + dy * h;
      float pw  = expf(dw) * w;
      float ph  = expf(dh) * h;
      float x1 = fmaxf(pcx - 0.5f * pw, 0.0f);
      float y1 = pcy - 0.5f * ph;
      x1 = fmaxf(x1, 0.0f);
      y1 = fmaxf(y1, 0.0f);
      float x2 = fminf(pcx + 0.5f * pw, IMG_W);
      float y2 = fminf(pcy + 0.5f * ph, IMG_H);
      obox[a] = make_float4(x1, y1, x2, y2);

      float s    = scb[a];
      bool valid = (s > 0.05f);
      localcnt  += valid ? 1 : 0;
      float key  = valid ? -s : __int_as_float(0x7f800000);  // +inf if invalid
      skey[a] = ((unsigned long long)enc_f32(key) << 32) | (unsigned)a;
    }
    atomicAdd(cntS, localcnt);
    __syncthreads();

    // stable bitonic sort ascending (unique keys: idx in low 32 bits)
    for (int k = 2; k <= NA; k <<= 1) {
      for (int j = k >> 1; j > 0; j >>= 1) {
        for (int m = tid; m < NA; m += 256) {
          int mx = m ^ j;
          if (mx > m) {
            unsigned long long va = skey[m];
            unsigned long long vb = skey[mx];
            bool up = ((m & k) == 0);
            if ((va > vb) == up) { skey[m] = vb; skey[mx] = va; }
          }
        }
        __syncthreads();
      }
    }

    unsigned long long* pk = skeyG + (size_t)bc * NA;
    float4* pb = sboxG + (size_t)bc * NA;
#pragma unroll
    for (int m = 0; m < 4; ++m) {
      int r = tid + m * 256;
      unsigned long long kv = skey[r];
      int orig = (int)(unsigned)kv;
      pk[r] = kv;
      pb[r] = obox[orig];
    }
    if (tid == 0) nvalidG[bc] = *cntS;

  } else {
    // ================= per-batch symmetric W matrix =================
    const int wb   = blockIdx.x - NP;    // 0..31
    const int b    = wb >> 4;
    const int rblk = wb & 15;
    const int lane = tid & 63;
    const int wq   = tid >> 6;           // wave id 0..3

    float4* sb = (float4*)(smem);            // 16 KB
    float*  sa = (float*)(smem + 16384);     // 4 KB

    const float* regb = reg_pred + (size_t)b * 4 * NA;
    for (int a = tid; a < NA; a += 256) {
      float4 an = ((const float4*)anchors)[a];
      float w  = an.z - an.x;
      float h  = an.w - an.y;
      float cx = an.x + 0.5f * w;
      float cy = an.y + 0.5f * h;
      float dx = regb[0 * NA + a] * 0.1f;
      float dy = regb[1 * NA + a] * 0.1f;
      float dw = regb[2 * NA + a] * 0.2f;
      float dh = regb[3 * NA + a] * 0.2f;
      float pcx = cx + dx * w;
      float pcy = cy + dy * h;
      float pw  = expf(dw) * w;
      float ph  = expf(dh) * h;
      float x1 = fmaxf(pcx - 0.5f * pw, 0.0f);
      float y1 = pcy - 0.5f * ph;
      x1 = fmaxf(x1, 0.0f);
      y1 = fmaxf(y1, 0.0f);
      float x2 = fminf(pcx + 0.5f * pw, IMG_W);
      float y2 = fminf(pcy + 0.5f * ph, IMG_H);
      float4 bx = make_float4(x1, y1, x2, y2);
      sb[a] = bx;
      sa[a] = (bx.z - bx.x) * (bx.w - bx.y);
    }
    __syncthreads();

    const int r = rblk * 64 + lane;      // this lane's row
    float4 br = sb[r];
    float  ar = sa[r];
    unsigned long long* wrow = W + ((size_t)b * NA + r) * NWORD;

#pragma unroll
    for (int k2 = 0; k2 < 4; ++k2) {
      const int kw = wq * 4 + k2;        // word index 0..15
      const int jbase = kw * 64;
      unsigned long long bits = 0ull;
#pragma unroll 8
      for (int jj = 0; jj < 64; ++jj) {
        float4 bj = sb[jbase + jj];      // wave-broadcast
        float  aj = sa[jbase + jj];
        float ix1 = fmaxf(br.x, bj.x);
        float iy1 = fmaxf(br.y, bj.y);
        float ix2 = fminf(br.z, bj.z);
        float iy2 = fminf(br.w, bj.w);
        float inter = fmaxf(ix2 - ix1, 0.0f) * fmaxf(iy2 - iy1, 0.0f);
        float un = fmaxf((ar + aj) - inter, 1e-9f);
        bool sup = ((inter + inter) - un) > un * 5.9604644775390625e-8f;
        bits |= sup ? (1ull << jj) : 0ull;
      }
      wrow[kw] = bits;
    }
  }
}

// ---------------------------------------------------------------------------
// K2: greedy scan (verified r6 compute path) + double-buffered row staging:
// chunk c+1's 16 global loads per lane are issued into registers before
// chunk c's compute, hiding the L2 drain behind the ballot/gather work.
// ---------------------------------------------------------------------------
__global__ __launch_bounds__(64) void scan_kernel(
    const unsigned long long* __restrict__ skeyG,
    const float4* __restrict__ sboxG,
    const unsigned long long* __restrict__ W,     // (B, NA, NWORD)
    const int* __restrict__ nvalidG,
    float* __restrict__ out)              // (NP, NA, 5)
{
  const int p    = blockIdx.x;
  const int b    = p / NCLS;
  const int lane = threadIdx.x;

  __shared__ unsigned long long rowsL[64 * 17];    // 8704 B (136B row stride)
  __shared__ int oL[NA];                           // 4 KB sorted->orig map
  __shared__ unsigned long long KorigL[NWORD];     // kept set, orig space
  __shared__ unsigned long long keptS[NWORD];
  __shared__ __align__(16) float outAll[NA * 5];   // 20 KB

  if (lane < NWORD) { KorigL[lane] = 0ull; keptS[lane] = 0ull; }

  const int nv = nvalidG[p];
  const int nchunk = (nv + 63) >> 6;
  const unsigned long long* pk = skeyG + (size_t)p * NA;
  const unsigned long long* Wb = W + (size_t)b * NA * NWORD;

  // load all sorted->orig indices
#pragma unroll
  for (int it = 0; it < NWORD; ++it) {
    int r = it * 64 + lane;
    oL[r] = (int)(unsigned)pk[r];
  }
  __syncthreads();

  // lane's staging slots: rows t*4 + (lane>>4), word lane&15
  const int rsub = lane >> 4;
  const int wsub = lane & 15;

  // preload chunk 0 rows into registers
  unsigned long long pre[16];
  if (nchunk > 0) {
#pragma unroll
    for (int t = 0; t < 16; ++t) {
      int orow = oL[t * 4 + rsub];
      pre[t] = Wb[(size_t)orow * NWORD + wsub];
    }
  }

  for (int c = 0; c < nchunk; ++c) {
    // commit prefetched rows to LDS
#pragma unroll
    for (int t = 0; t < 16; ++t)
      rowsL[(t * 4 + rsub) * 17 + wsub] = pre[t];
    __syncthreads();

    // issue next chunk's loads (drain overlaps this chunk's compute)
    if (c + 1 < nchunk) {
#pragma unroll
      for (int t = 0; t < 16; ++t) {
        int orow = oL[(c + 1) * 64 + t * 4 + rsub];
        pre[t] = Wb[(size_t)orow * NWORD + wsub];
      }
    }

    const int sMine = c * 64 + lane;
    const int oMine = oL[sMine];

    // pre-suppressed by earlier-chunk kept boxes
    unsigned long long pp = 0ull;
#pragma unroll
    for (int k = 0; k < NWORD; ++k)
      pp |= rowsL[lane * 17 + k] & KorigL[k];

    // within-chunk diag gather (broadcast reads, conflict-free)
    const int wsel = oMine >> 6;
    const int bsel = oMine & 63;
    unsigned long long diag = 0ull;
#pragma unroll 16
    for (int si = 0; si < 64; ++si) {
      unsigned long long rw = rowsL[si * 17 + wsel];
      diag |= ((rw >> bsel) & 1ull) << si;
    }
    diag &= (1ull << lane) - 1ull;       // only si < lane (lane 0 -> 0)

    // fixed-point decided loop (verified r5/r6)
    unsigned long long valid = __ballot(sMine < nv);
    unsigned long long S     = __ballot(pp != 0ull);
    unsigned long long K  = 0ull;
    unsigned long long Dd = (~valid) | S;
    for (int round = 0; round < 64; ++round) {
      unsigned long long und = ~Dd;
      if (und == 0ull) break;                        // wave-uniform
      bool me_und  = (und >> lane) & 1ull;
      bool blocked = (diag & (K | und)) != 0ull;
      bool isSupp  = (diag & K) != 0ull;
      unsigned long long kb  = __ballot(me_und && !blocked);
      unsigned long long sbm = __ballot(me_und && isSupp);
      K  |= kb;
      Dd |= kb | sbm;
    }
    if (lane == 0) keptS[c] = K;

    // add kept boxes to K_orig (orig space)
    if ((K >> lane) & 1ull)
      atomicOr(&KorigL[oMine >> 6], 1ull << (oMine & 63));
    __syncthreads();
  }
  __syncthreads();   // keptS visible

  // stage output in original anchor order (verified r4-r6 path)
  const float4* pb = sboxG + (size_t)p * NA;
#pragma unroll 4
  for (int it = 0; it < NWORD; ++it) {
    int r = it * 64 + lane;
    unsigned long long kv = pk[r];
    float4 bx = pb[r];
    int orig = (int)(unsigned)kv;
    bool kp = (keptS[it] >> lane) & 1ull;
    float sc = 0.0f;
    float4 ob = make_float4(0.0f, 0.0f, 0.0f, 0.0f);
    if (kp) {
      sc = -__uint_as_float(~(unsigned)(kv >> 32));  // exact original score
      ob = bx;
    }
    float* oa = outAll + (size_t)orig * 5;
    oa[0] = sc; oa[1] = ob.x; oa[2] = ob.y; oa[3] = ob.z; oa[4] = ob.w;
  }
  __syncthreads();

  float4* og = (float4*)(out + (size_t)p * NA * 5);
  const float4* ol = (const float4*)outAll;
  for (int t4 = lane; t4 < (NA * 5) / 4; t4 += 64) og[t4] = ol[t4];
}

// ---------------------------------------------------------------------------
// Fallback: round-1 monolithic kernel (used only if ws_size is too small)
// ---------------------------------------------------------------------------
__global__ __launch_bounds__(256) void nms_mono_kernel(
    const float* __restrict__ cls_pred,
    const float* __restrict__ reg_pred,
    const float* __restrict__ anchors,
    float* __restrict__ out)
{
#pragma clang fp contract(off)
  const int bc  = blockIdx.x;
  const int b   = bc / NCLS;
  const int tid = threadIdx.x;
  const int BNT = 256, BPT = 4;

  __shared__ __align__(16) unsigned char smem[49152];
  float4*             obox  = (float4*)(smem);
  float4*             sbox  = (float4*)(smem + 16384);
  unsigned long long* skey  = (unsigned long long*)(smem + 32768);
  float*              sarea = (float*)(smem + 40960);
  int*                keepL = (int*)(smem + 45056);

  const float* regb = reg_pred + (size_t)b * 4 * NA;
  const float* scb  = cls_pred + (size_t)bc * NA;
  for (int a = tid; a < NA; a += BNT) {
    float4 an = ((const float4*)anchors)[a];
    float w  = an.z - an.x;
    float h  = an.w - an.y;
    float cx = an.x + 0.5f * w;
    float cy = an.y + 0.5f * h;
    float dx = regb[0 * NA + a] * 0.1f;
    float dy = regb[1 * NA + a] * 0.1f;
    float dw = regb[2 * NA + a] * 0.2f;
    float dh = regb[3 * NA + a] * 0.2f;
    float pcx = cx + dx * w;
    float pcy = cy + dy * h;
    float pw  = expf(dw) * w;
    float ph  = expf(dh) * h;
    float x1 = fmaxf(fmaxf(pcx - 0.5f * pw, 0.0f), 0.0f);
    float y1 = fmaxf(pcy - 0.5f * ph, 0.0f);
    float x2 = fminf(pcx + 0.5f * pw, IMG_W);
    float y2 = fminf(pcy + 0.5f * ph, IMG_H);
    obox[a] = make_float4(x1, y1, x2, y2);
    float s   = scb[a];
    float key = (s > 0.05f) ? -s : __int_as_float(0x7f800000);
    skey[a] = ((unsigned long long)enc_f32(key) << 32) | (unsigned)a;
  }
  __syncthreads();
  for (int k = 2; k <= NA; k <<= 1) {
    for (int j = k >> 1; j > 0; j >>= 1) {
      for (int m = tid; m < NA; m += BNT) {
        int mx = m ^ j;
        if (mx > m) {
          unsigned long long va = skey[m];
          unsigned long long vb = skey[mx];
          bool up = ((m & k) == 0);
          if ((va > vb) == up) { skey[m] = vb; skey[mx] = va; }
        }
      }
      __syncthreads();
    }
  }
  float4 bj[4]; float aj[4]; int kj[4];
#pragma unroll
  for (int m = 0; m < BPT; ++m) {
    int r = tid + m * BNT;
    unsigned long long kv = skey[r];
    int orig = (int)(unsigned)kv;
    float4 bx = obox[orig];
    sbox[r] = bx;
    float ar = (bx.z - bx.x) * (bx.w - bx.y);
    sarea[r] = ar;
    int kp = ((unsigned)(kv >> 32) != 0xFF800000u) ? 1 : 0;
    keepL[r] = kp;
    bj[m] = bx; aj[m] = ar; kj[m] = kp;
  }
  for (int i = 0; i < NA; ++i) {
    __syncthreads();
    if (keepL[i] == 0) continue;
    float4 bi = sbox[i];
    float  ai = sarea[i];
#pragma unroll
    for (int m = 0; m < BPT; ++m) {
      int j = tid + m * BNT;
      if (j > i && kj[m]) {
        float ix1 = fmaxf(bi.x, bj[m].x);
        float iy1 = fmaxf(bi.y, bj[m].y);
        float ix2 = fminf(bi.z, bj[m].z);
        float iy2 = fminf(bi.w, bj[m].w);
        float inter = fmaxf(ix2 - ix1, 0.0f) * fmaxf(iy2 - iy1, 0.0f);
        float un = fmaxf(ai + aj[m] - inter, 1e-9f);
        if (inter / un > 0.5f) { kj[m] = 0; keepL[j] = 0; }
      }
    }
  }
  __syncthreads();
  float4* outbox = obox;
  float*  outsc  = sarea;
#pragma unroll
  for (int m = 0; m < BPT; ++m) {
    int r = tid + m * BNT;
    unsigned long long kv = skey[r];
    int orig = (int)(unsigned)kv;
    float  sc = 0.0f;
    float4 bx = make_float4(0.0f, 0.0f, 0.0f, 0.0f);
    if (kj[m]) {
      sc = -__uint_as_float(~(unsigned)(kv >> 32));
      bx = sbox[r];
    }
    outsc[orig]  = sc;
    outbox[orig] = bx;
  }
  __syncthreads();
  float* ob = out + (size_t)bc * NA * 5;
  for (int a = tid; a < NA; a += BNT) {
    float4 bx = outbox[a];
    float* o = ob + (size_t)a * 5;
    o[0] = outsc[a]; o[1] = bx.x; o[2] = bx.y; o[3] = bx.z; o[4] = bx.w;
  }
}

// ---------------------------------------------------------------------------
extern "C" void kernel_launch(void* const* d_in, const int* in_sizes, int n_in,
                              void* d_out, int out_size, void* d_ws, size_t ws_size,
                              hipStream_t stream) {
  const float* cls = (const float*)d_in[1];
  const float* reg = (const float*)d_in[2];
  const float* anc = (const float*)d_in[3];
  float* out = (float*)d_out;

  // workspace layout (256B-aligned blocks)
  const size_t off_key = 0;                                    // NP*NA*8
  const size_t off_box = off_key + (size_t)NP * NA * 8;        // NP*NA*16
  const size_t off_w   = off_box + (size_t)NP * NA * 16;       // B*NA*NWORD*8
  const size_t off_nv  = off_w + (size_t)BATCH * NA * NWORD * 8;
  const size_t need    = off_nv + (size_t)NP * sizeof(int);

  if (ws_size < need) {
    nms_mono_kernel<<<dim3(NP), dim3(256), 0, stream>>>(cls, reg, anc, out);
    return;
  }

  char* ws = (char*)d_ws;
  unsigned long long* skeyG = (unsigned long long*)(ws + off_key);
  float4*             sboxG = (float4*)(ws + off_box);
  unsigned long long* Wm    = (unsigned long long*)(ws + off_w);
  int*                nvG   = (int*)(ws + off_nv);

  prep_kernel<<<dim3(NP + BATCH * NWORD), dim3(256), 0, stream>>>(
      cls, reg, anc, skeyG, sboxG, nvG, Wm);
  scan_kernel<<<dim3(NP), dim3(64), 0, stream>>>(skeyG, sboxG, Wm, nvG, out);
}